// Round 8
// baseline (5505.506 us; speedup 1.0000x reference)
//
#include <hip/hip_runtime.h>
#include <hip/hip_fp16.h>

#define N 4096
#define KX 3072
#define KZ 128
#define NBT (N / 128)               // 32 tile-rows for the MFMA dist kernel
#define NTRI2 (NBT * (NBT + 1) / 2) // 528 triangular tiles

typedef __attribute__((ext_vector_type(8))) short bf16x8;
typedef __attribute__((ext_vector_type(4))) float f32x4;

// ---------- helpers ----------
__device__ __forceinline__ float2 up2(unsigned v) {
  __half2 h = __builtin_bit_cast(__half2, v);
  return __half22float2(h);
}

__device__ __forceinline__ short f2bf(float f) {  // RTN-even fp32 -> bf16
  unsigned u = __float_as_uint(f);
  u += 0x7fffu + ((u >> 16) & 1u);
  return (short)(u >> 16);
}

// DPP-based partial min (within 16-lane rows); CTRL is a compile-time constant.
template <int CTRL>
__device__ __forceinline__ float dpp_fmin(float x) {
  int y = __builtin_amdgcn_update_dpp(0, __float_as_int(x), CTRL, 0xF, 0xF, true);
  return fminf(x, __int_as_float(y));
}
__device__ __forceinline__ float xmin16(float x) {
  int t = __builtin_amdgcn_ds_swizzle(__float_as_int(x), 0x401F);  // xor 16
  return fminf(x, __int_as_float(t));
}
__device__ __forceinline__ float xmin32(float x) {
  return fminf(x, __shfl_xor(x, 32));
}

// ---------- fp32 -> bf16 conversion (8 elems/thread, grid-stride) ----------
__global__ __launch_bounds__(256) void cvt_bf16_kernel(const float* __restrict__ X,
                                                       short* __restrict__ Xb, int n8) {
  int stride = gridDim.x * 256;
  for (int i = blockIdx.x * 256 + threadIdx.x; i < n8; i += stride) {
    float4 a = *(const float4*)(X + (size_t)i * 8);
    float4 b = *(const float4*)(X + (size_t)i * 8 + 4);
    bf16x8 o;
    o[0] = f2bf(a.x); o[1] = f2bf(a.y); o[2] = f2bf(a.z); o[3] = f2bf(a.w);
    o[4] = f2bf(b.x); o[5] = f2bf(b.y); o[6] = f2bf(b.z); o[7] = f2bf(b.w);
    *(bf16x8*)(Xb + (size_t)i * 8) = o;
  }
}

// ---------- row squared norms (exact fp32) ----------
__global__ __launch_bounds__(256) void sqnorm_kernel(const float* __restrict__ X, int K,
                                                     float* __restrict__ sq) {
  int row = blockIdx.x;
  const float4* xr = (const float4*)(X + (size_t)row * K);
  float s = 0.f;
  int n4 = K >> 2;
  for (int i = threadIdx.x; i < n4; i += 256) {
    float4 v = xr[i];
    s += v.x * v.x + v.y * v.y + v.z * v.z + v.w * v.w;
  }
  for (int off = 32; off > 0; off >>= 1) s += __shfl_down(s, off);
  __shared__ float wsum[4];
  int lane = threadIdx.x & 63, w = threadIdx.x >> 6;
  if (lane == 0) wsum[w] = s;
  __syncthreads();
  if (threadIdx.x == 0) {
    float t = 0.f;
    #pragma unroll
    for (int i = 0; i < 4; ++i) t += wsum[i];
    sq[row] = t;
  }
}

// ---------- MFMA bf16 distance GEMM (round-7 proven) ----------
__global__ __launch_bounds__(256) void dist_mfma_kernel(const short* __restrict__ Xb, int K,
                                                        const float* __restrict__ sq,
                                                        __half* __restrict__ D) {
  int t = blockIdx.x;
  int br = (int)((sqrtf(8.0f * (float)t + 1.0f) - 1.0f) * 0.5f);
  while ((br + 1) * (br + 2) / 2 <= t) ++br;
  while (br * (br + 1) / 2 > t) --br;
  int bc = t - br * (br + 1) / 2;
  int i0 = br * 128, j0 = bc * 128;

  __shared__ short As[128][40];
  __shared__ short Bs[128][40];

  int tid = threadIdx.x, lane = tid & 63, w = tid >> 6;
  int wr = w >> 1, wc = w & 1;
  int fr = lane & 15, fc = lane >> 4;

  f32x4 acc[4][4];
  #pragma unroll
  for (int m = 0; m < 4; ++m)
    #pragma unroll
    for (int nn = 0; nn < 4; ++nn)
      acc[m][nn] = (f32x4){0.f, 0.f, 0.f, 0.f};

  for (int k0 = 0; k0 < K; k0 += 32) {
    #pragma unroll
    for (int u = 0; u < 2; ++u) {
      int f = tid + u * 256;
      int r = f >> 2;
      int c = (f & 3) * 8;
      *(bf16x8*)&As[r][c] = *(const bf16x8*)(Xb + (size_t)(i0 + r) * K + k0 + c);
      *(bf16x8*)&Bs[r][c] = *(const bf16x8*)(Xb + (size_t)(j0 + r) * K + k0 + c);
    }
    __syncthreads();
    bf16x8 af[4], bg[4];
    #pragma unroll
    for (int m = 0; m < 4; ++m)
      af[m] = *(const bf16x8*)&As[wr * 64 + m * 16 + fr][fc * 8];
    #pragma unroll
    for (int nn = 0; nn < 4; ++nn)
      bg[nn] = *(const bf16x8*)&Bs[wc * 64 + nn * 16 + fr][fc * 8];
    #pragma unroll
    for (int m = 0; m < 4; ++m)
      #pragma unroll
      for (int nn = 0; nn < 4; ++nn)
        acc[m][nn] = __builtin_amdgcn_mfma_f32_16x16x32_bf16(af[m], bg[nn], acc[m][nn], 0, 0, 0);
    __syncthreads();
  }

  #pragma unroll
  for (int m = 0; m < 4; ++m) {
    #pragma unroll
    for (int nn = 0; nn < 4; ++nn) {
      int gj = j0 + wc * 64 + nn * 16 + fr;
      float sqj = sq[gj];
      #pragma unroll
      for (int e = 0; e < 4; ++e) {
        int gi = i0 + wr * 64 + m * 16 + fc * 4 + e;
        float d2 = sq[gi] + sqj - 2.0f * acc[m][nn][e];
        float d = sqrtf(fmaxf(d2, 0.0f));
        __half h = __float2half(d);
        D[(size_t)gi * N + gj] = h;
        D[(size_t)gj * N + gi] = h;
      }
    }
  }
}

// ---------- MST: split-argmin pipeline (exact reference semantics) ----------
// argmin(min(md,row) with INF at j) == mincombine(argmin(md w/ INF at j),
// argmin(row w/ INF at j)) — exact incl. first-index ties via u64 keys.
// A-reduce (over md) runs UNDER the row-load latency; only the B-reduce (over
// the fresh row) is post-load. The md/par update is DEFERRED into the next
// step's load window (row carried in registers pr0..pr7). Eager INF at j +
// post-update re-INF reproduce the reference's update-then-INF order exactly
// (incl. resurrection of in-tree nodes and par[j]=j self-parenting).
#define LMIN8(v0,v1,v2,v3,v4,v5,v6,v7, OUTV, OUTI)                        \
  { bool c_; float a01,a23,a45,a67,a03,a47; int b01,b23,b45,b67,b03,b47;  \
    c_ = v1<v0; a01=c_?v1:v0; b01=c_?1:0;                                 \
    c_ = v3<v2; a23=c_?v3:v2; b23=c_?3:2;                                 \
    c_ = v5<v4; a45=c_?v5:v4; b45=c_?5:4;                                 \
    c_ = v7<v6; a67=c_?v7:v6; b67=c_?7:6;                                 \
    c_ = a23<a01; a03=c_?a23:a01; b03=c_?b23:b01;                         \
    c_ = a67<a45; a47=c_?a67:a45; b47=c_?b67:b45;                         \
    c_ = a47<a03; OUTV=c_?a47:a03; OUTI=c_?b47:b03; }

#define WREDUCE_WRITE(P, BV, BI, SLOT)  {                                  \
    float mv_ = BV;                                                        \
    mv_ = dpp_fmin<0xB1>(mv_);  mv_ = dpp_fmin<0x4E>(mv_);                 \
    mv_ = dpp_fmin<0x141>(mv_); mv_ = dpp_fmin<0x140>(mv_);                \
    mv_ = xmin16(mv_); mv_ = xmin32(mv_);                                  \
    unsigned long long ball_ = __ballot((BV) == mv_);                      \
    int first_ = __ffsll(ball_) - 1;                                       \
    if (lane == first_)                                                    \
      skey[P][SLOT] = ((unsigned long long)__float_as_uint(mv_) << 32) | (unsigned)(BI); }

__global__ __launch_bounds__(512) void mst_kernel(const __half* __restrict__ Dx,
                                                  const __half* __restrict__ Dz,
                                                  int2* __restrict__ ex,
                                                  int2* __restrict__ ez) {
  const __half* __restrict__ D = (blockIdx.x == 0) ? Dx : Dz;
  int2* __restrict__ edges = (blockIdx.x == 0) ? ex : ez;
  const float INF = __builtin_inff();

  int tid = threadIdx.x;      // 0..511
  int lane = tid & 63;
  int w = tid >> 6;           // wave 0..7
  int base = tid * 8;         // nodes [base, base+8)

  float md0, md1, md2, md3, md4, md5, md6, md7;
  int par0 = 0, par1 = 0, par2 = 0, par3 = 0, par4 = 0, par5 = 0, par6 = 0, par7 = 0;
  {
    uint4 u = *(const uint4*)(D + base);
    float2 f;
    f = up2(u.x); md0 = f.x; md1 = f.y;
    f = up2(u.y); md2 = f.x; md3 = f.y;
    f = up2(u.z); md4 = f.x; md5 = f.y;
    f = up2(u.w); md6 = f.x; md7 = f.y;
  }
  if (tid == 0) md0 = INF;  // node 0 starts in tree

  __shared__ unsigned long long skey[2][16];

  // ---- prologue: j0 = argmin(initial md) via A-reduce only (parity 1)
  int j;
  {
    float av; int ai;
    LMIN8(md0, md1, md2, md3, md4, md5, md6, md7, av, ai);
    int abi = base + ai;
    WREDUCE_WRITE(1, av, abi, w);
    if (lane == 0) skey[1][8 + w] = ~0ULL;
    __syncthreads();
    unsigned long long key = skey[1][0];
    #pragma unroll
    for (int k = 1; k < 16; ++k) {
      unsigned long long o = skey[1][k];
      key = (o < key) ? o : key;
    }
    j = (int)(unsigned)key;
  }

  // carried state: previous row (registers) + its position
  float pr0 = INF, pr1 = INF, pr2 = INF, pr3 = INF,
        pr4 = INF, pr5 = INF, pr6 = INF, pr7 = INF;
  int jp = 0, jtprev = -1, jlprev = 0;

  for (int t = 0; t < N - 1; ++t) {
    int p = t & 1;
    int jt = j >> 3, jl = j & 7;

    // 1. issue this step's row load (latency hides steps 2-5)
    uint4 u = *(const uint4*)(D + (size_t)j * N + base);

    // 2. deferred md/par update with the PREVIOUS row (reference step t-1 tail)
    #define DUPD(q, prq) { bool up_ = prq < md##q; md##q = up_ ? prq : md##q; par##q = up_ ? jp : par##q; }
    DUPD(0, pr0) DUPD(1, pr1) DUPD(2, pr2) DUPD(3, pr3)
    DUPD(4, pr4) DUPD(5, pr5) DUPD(6, pr6) DUPD(7, pr7)
    #undef DUPD
    if (jtprev == tid) {   // re-INF at j_{t-1} (reference: .at[j].set(inf) after min)
      if      (jlprev == 0) md0 = INF;
      else if (jlprev == 1) md1 = INF;
      else if (jlprev == 2) md2 = INF;
      else if (jlprev == 3) md3 = INF;
      else if (jlprev == 4) md4 = INF;
      else if (jlprev == 5) md5 = INF;
      else if (jlprev == 6) md6 = INF;
      else                  md7 = INF;
    }

    // 3. record edge t (par now == reference parent state at start of step t)
    if (jt == tid) {
      int pj = (jl == 0) ? par0 : (jl == 1) ? par1 : (jl == 2) ? par2 :
               (jl == 3) ? par3 : (jl == 4) ? par4 : (jl == 5) ? par5 :
               (jl == 6) ? par6 : par7;
      edges[t] = make_int2(pj, j);
    }

    // 4. eager INF at j (safe: update-comparison result at j unchanged, see notes)
    if (jt == tid) {
      if      (jl == 0) md0 = INF;
      else if (jl == 1) md1 = INF;
      else if (jl == 2) md2 = INF;
      else if (jl == 3) md3 = INF;
      else if (jl == 4) md4 = INF;
      else if (jl == 5) md5 = INF;
      else if (jl == 6) md6 = INF;
      else              md7 = INF;
    }

    // 5. A-reduce over md (no dependence on the in-flight load)
    {
      float av; int ai;
      LMIN8(md0, md1, md2, md3, md4, md5, md6, md7, av, ai);
      int abi = base + ai;
      WREDUCE_WRITE(p, av, abi, w);
    }

    // 6. B-reduce over the fresh row (waits for the load here), j masked to INF
    {
      float2 f;
      f = up2(u.x); pr0 = f.x; pr1 = f.y;
      f = up2(u.y); pr2 = f.x; pr3 = f.y;
      f = up2(u.z); pr4 = f.x; pr5 = f.y;
      f = up2(u.w); pr6 = f.x; pr7 = f.y;
      bool self = (jt == tid);
      float m0 = (self && jl == 0) ? INF : pr0;
      float m1 = (self && jl == 1) ? INF : pr1;
      float m2 = (self && jl == 2) ? INF : pr2;
      float m3 = (self && jl == 3) ? INF : pr3;
      float m4 = (self && jl == 4) ? INF : pr4;
      float m5 = (self && jl == 5) ? INF : pr5;
      float m6 = (self && jl == 6) ? INF : pr6;
      float m7 = (self && jl == 7) ? INF : pr7;
      float bv; int bi;
      LMIN8(m0, m1, m2, m3, m4, m5, m6, m7, bv, bi);
      int bbi = base + bi;
      WREDUCE_WRITE(p, bv, bbi, 8 + w);
    }

    // 7. bookkeeping for the deferred update
    jp = j; jtprev = jt; jlprev = jl;

    // 8. single barrier; combine all 16 slot keys (min == exact argmin w/ ties)
    __syncthreads();
    unsigned long long key = skey[p][0];
    #pragma unroll
    for (int k = 1; k < 16; ++k) {
      unsigned long long o = skey[p][k];
      key = (o < key) ? o : key;
    }
    j = (int)(unsigned)key;
  }
}

// ---------- final loss ----------
__global__ __launch_bounds__(1024) void loss_kernel(const __half* __restrict__ Dx,
                                                    const __half* __restrict__ Dz,
                                                    const int2* __restrict__ ex,
                                                    const int2* __restrict__ ez,
                                                    float* __restrict__ out) {
  int tid = threadIdx.x;
  float s = 0.f;
  const int M = N - 1;
  for (int e = tid; e < 2 * M; e += 1024) {
    int2 uv = (e < M) ? ex[e] : ez[e - M];
    size_t off = (size_t)uv.x * N + uv.y;
    float dx = __half2float(Dx[off]);
    float dz = __half2float(Dz[off]);
    float d = dx - dz;
    s += d * d;
  }
  for (int off = 32; off > 0; off >>= 1) s += __shfl_down(s, off);
  __shared__ float wsum[16];
  int lane = tid & 63, w = tid >> 6;
  if (lane == 0) wsum[w] = s;
  __syncthreads();
  if (tid == 0) {
    float t = 0.f;
    #pragma unroll
    for (int i = 0; i < 16; ++i) t += wsum[i];
    out[0] = 0.5f * t;
  }
}

// ---------- launch ----------
extern "C" void kernel_launch(void* const* d_in, const int* in_sizes, int n_in,
                              void* d_out, int out_size, void* d_ws, size_t ws_size,
                              hipStream_t stream) {
  const float* x = (const float*)d_in[0];
  const float* z = (const float*)d_in[1];
  float* out = (float*)d_out;
  char* ws = (char*)d_ws;

  __half* Dx = (__half*)ws;                       // 32 MB
  __half* Dz = Dx + (size_t)N * N;                // 32 MB
  short* Xb = (short*)(Dz + (size_t)N * N);       // 24 MB
  short* Zb = Xb + (size_t)N * KX;                // 1 MB
  float* sqx = (float*)(Zb + (size_t)N * KZ);
  float* sqz = sqx + N;
  int2* ex = (int2*)(sqz + N);
  int2* ez = ex + (N - 1);

  cvt_bf16_kernel<<<2048, 256, 0, stream>>>(x, Xb, N * KX / 8);
  cvt_bf16_kernel<<<256, 256, 0, stream>>>(z, Zb, N * KZ / 8);
  sqnorm_kernel<<<N, 256, 0, stream>>>(x, KX, sqx);
  sqnorm_kernel<<<N, 256, 0, stream>>>(z, KZ, sqz);
  dist_mfma_kernel<<<NTRI2, 256, 0, stream>>>(Xb, KX, sqx, Dx);
  dist_mfma_kernel<<<NTRI2, 256, 0, stream>>>(Zb, KZ, sqz, Dz);
  mst_kernel<<<2, 512, 0, stream>>>(Dx, Dz, ex, ez);
  loss_kernel<<<1, 1024, 0, stream>>>(Dx, Dz, ex, ez, out);
}

// Round 9
// 2659.262 us; speedup vs baseline: 2.0703x; 2.0703x over previous
//
#include <hip/hip_runtime.h>
#include <hip/hip_fp16.h>

#define N 4096
#define KX 3072
#define KZ 128
#define NBT (N / 128)               // 32 tile-rows for the MFMA dist kernel
#define NTRI2 (NBT * (NBT + 1) / 2) // 528 triangular tiles

typedef __attribute__((ext_vector_type(8))) short bf16x8;
typedef __attribute__((ext_vector_type(4))) float f32x4;

// ---------- helpers ----------
__device__ __forceinline__ short f2bf(float f) {  // RTN-even fp32 -> bf16
  unsigned u = __float_as_uint(f);
  u += 0x7fffu + ((u >> 16) & 1u);
  return (short)(u >> 16);
}

__device__ __forceinline__ unsigned umin2(unsigned a, unsigned b) { return a < b ? a : b; }

// DPP-based partial u32-min (within 16-lane rows); CTRL compile-time.
template <int CTRL>
__device__ __forceinline__ unsigned dpp_umin(unsigned x) {
  unsigned y = (unsigned)__builtin_amdgcn_update_dpp(0, (int)x, CTRL, 0xF, 0xF, true);
  return umin2(x, y);
}

// ---------- fp32 -> bf16 conversion (8 elems/thread, grid-stride) ----------
__global__ __launch_bounds__(256) void cvt_bf16_kernel(const float* __restrict__ X,
                                                       short* __restrict__ Xb, int n8) {
  int stride = gridDim.x * 256;
  for (int i = blockIdx.x * 256 + threadIdx.x; i < n8; i += stride) {
    float4 a = *(const float4*)(X + (size_t)i * 8);
    float4 b = *(const float4*)(X + (size_t)i * 8 + 4);
    bf16x8 o;
    o[0] = f2bf(a.x); o[1] = f2bf(a.y); o[2] = f2bf(a.z); o[3] = f2bf(a.w);
    o[4] = f2bf(b.x); o[5] = f2bf(b.y); o[6] = f2bf(b.z); o[7] = f2bf(b.w);
    *(bf16x8*)(Xb + (size_t)i * 8) = o;
  }
}

// ---------- row squared norms (exact fp32) ----------
__global__ __launch_bounds__(256) void sqnorm_kernel(const float* __restrict__ X, int K,
                                                     float* __restrict__ sq) {
  int row = blockIdx.x;
  const float4* xr = (const float4*)(X + (size_t)row * K);
  float s = 0.f;
  int n4 = K >> 2;
  for (int i = threadIdx.x; i < n4; i += 256) {
    float4 v = xr[i];
    s += v.x * v.x + v.y * v.y + v.z * v.z + v.w * v.w;
  }
  for (int off = 32; off > 0; off >>= 1) s += __shfl_down(s, off);
  __shared__ float wsum[4];
  int lane = threadIdx.x & 63, w = threadIdx.x >> 6;
  if (lane == 0) wsum[w] = s;
  __syncthreads();
  if (threadIdx.x == 0) {
    float t = 0.f;
    #pragma unroll
    for (int i = 0; i < 4; ++i) t += wsum[i];
    sq[row] = t;
  }
}

// ---------- MFMA bf16 distance GEMM (round-7 proven) ----------
__global__ __launch_bounds__(256) void dist_mfma_kernel(const short* __restrict__ Xb, int K,
                                                        const float* __restrict__ sq,
                                                        __half* __restrict__ D) {
  int t = blockIdx.x;
  int br = (int)((sqrtf(8.0f * (float)t + 1.0f) - 1.0f) * 0.5f);
  while ((br + 1) * (br + 2) / 2 <= t) ++br;
  while (br * (br + 1) / 2 > t) --br;
  int bc = t - br * (br + 1) / 2;
  int i0 = br * 128, j0 = bc * 128;

  __shared__ short As[128][40];
  __shared__ short Bs[128][40];

  int tid = threadIdx.x, lane = tid & 63, w = tid >> 6;
  int wr = w >> 1, wc = w & 1;
  int fr = lane & 15, fc = lane >> 4;

  f32x4 acc[4][4];
  #pragma unroll
  for (int m = 0; m < 4; ++m)
    #pragma unroll
    for (int nn = 0; nn < 4; ++nn)
      acc[m][nn] = (f32x4){0.f, 0.f, 0.f, 0.f};

  for (int k0 = 0; k0 < K; k0 += 32) {
    #pragma unroll
    for (int u = 0; u < 2; ++u) {
      int f = tid + u * 256;
      int r = f >> 2;
      int c = (f & 3) * 8;
      *(bf16x8*)&As[r][c] = *(const bf16x8*)(Xb + (size_t)(i0 + r) * K + k0 + c);
      *(bf16x8*)&Bs[r][c] = *(const bf16x8*)(Xb + (size_t)(j0 + r) * K + k0 + c);
    }
    __syncthreads();
    bf16x8 af[4], bg[4];
    #pragma unroll
    for (int m = 0; m < 4; ++m)
      af[m] = *(const bf16x8*)&As[wr * 64 + m * 16 + fr][fc * 8];
    #pragma unroll
    for (int nn = 0; nn < 4; ++nn)
      bg[nn] = *(const bf16x8*)&Bs[wc * 64 + nn * 16 + fr][fc * 8];
    #pragma unroll
    for (int m = 0; m < 4; ++m)
      #pragma unroll
      for (int nn = 0; nn < 4; ++nn)
        acc[m][nn] = __builtin_amdgcn_mfma_f32_16x16x32_bf16(af[m], bg[nn], acc[m][nn], 0, 0, 0);
    __syncthreads();
  }

  #pragma unroll
  for (int m = 0; m < 4; ++m) {
    #pragma unroll
    for (int nn = 0; nn < 4; ++nn) {
      int gj = j0 + wc * 64 + nn * 16 + fr;
      float sqj = sq[gj];
      #pragma unroll
      for (int e = 0; e < 4; ++e) {
        int gi = i0 + wr * 64 + m * 16 + fc * 4 + e;
        float d2 = sq[gi] + sqj - 2.0f * acc[m][nn][e];
        float d = sqrtf(fmaxf(d2, 0.0f));
        __half h = __float2half(d);
        D[(size_t)gi * N + gj] = h;
        D[(size_t)gj * N + gi] = h;
      }
    }
  }
}

// ---------- MST: u32-key deferred pipeline (exact reference semantics) ----------
// Key = (halfbits<<16)|node_idx: d>=0 so halfbits order-monotonic; ties pick
// lowest index (== reference argmin). md stored AS keys. Deferred update
// (round-8 hardware-verified semantics) runs under the row-load latency,
// pinned by sched_barrier(0). A-tree is pure v_min_u32 on registers (no LDS
// ops between load issue and use). Wave tail: 4 DPP stages + 3 readlane +
// scalar mins (no ds_swizzle/bpermute). 4B LDS slots, 8-slot combine.
#define INFK(idx) (0xFFFF0000u | (unsigned)(idx))

__global__ __launch_bounds__(512) void mst_kernel(const __half* __restrict__ Dx,
                                                  const __half* __restrict__ Dz,
                                                  int2* __restrict__ ex,
                                                  int2* __restrict__ ez) {
  const __half* __restrict__ D = (blockIdx.x == 0) ? Dx : Dz;
  int2* __restrict__ edges = (blockIdx.x == 0) ? ex : ez;

  int tid = threadIdx.x;      // 0..511
  int lane = tid & 63;
  int w = tid >> 6;           // wave 0..7
  int base = tid * 8;         // nodes [base, base+8)

  unsigned mdk0, mdk1, mdk2, mdk3, mdk4, mdk5, mdk6, mdk7;
  int par0 = 0, par1 = 0, par2 = 0, par3 = 0, par4 = 0, par5 = 0, par6 = 0, par7 = 0;
  {
    uint4 u = *(const uint4*)(D + base);
    mdk0 = (u.x << 16) | (unsigned)(base + 0);
    mdk1 = (u.x & 0xffff0000u) | (unsigned)(base + 1);
    mdk2 = (u.y << 16) | (unsigned)(base + 2);
    mdk3 = (u.y & 0xffff0000u) | (unsigned)(base + 3);
    mdk4 = (u.z << 16) | (unsigned)(base + 4);
    mdk5 = (u.z & 0xffff0000u) | (unsigned)(base + 5);
    mdk6 = (u.w << 16) | (unsigned)(base + 6);
    mdk7 = (u.w & 0xffff0000u) | (unsigned)(base + 7);
  }
  if (tid == 0) mdk0 = INFK(0);  // node 0 starts in tree

  __shared__ unsigned skey[2][8];

  // ---- prologue: j0 = argmin(initial md)
  int j;
  {
    unsigned x = umin2(umin2(umin2(mdk0, mdk1), umin2(mdk2, mdk3)),
                       umin2(umin2(mdk4, mdk5), umin2(mdk6, mdk7)));
    x = dpp_umin<0xB1>(x);   // xor 1
    x = dpp_umin<0x4E>(x);   // xor 2
    x = dpp_umin<0x141>(x);  // xor 4 (row_half_mirror)
    x = dpp_umin<0x140>(x);  // xor 8 (row_mirror)
    unsigned r0 = (unsigned)__builtin_amdgcn_readlane((int)x, 0);
    unsigned r1 = (unsigned)__builtin_amdgcn_readlane((int)x, 16);
    unsigned r2 = (unsigned)__builtin_amdgcn_readlane((int)x, 32);
    unsigned r3 = (unsigned)__builtin_amdgcn_readlane((int)x, 48);
    unsigned wm = umin2(umin2(r0, r1), umin2(r2, r3));
    if (lane == 0) skey[1][w] = wm;
    __syncthreads();
    uint4 A = ((const uint4*)&skey[1][0])[0];
    uint4 B = ((const uint4*)&skey[1][0])[1];
    unsigned k = umin2(umin2(umin2(A.x, A.y), umin2(A.z, A.w)),
                       umin2(umin2(B.x, B.y), umin2(B.z, B.w)));
    j = (int)(k & 0xFFFu);
  }

  // carried state: previous row keys (true values) + its position
  unsigned prk0 = 0xFFFFFFFFu, prk1 = 0xFFFFFFFFu, prk2 = 0xFFFFFFFFu, prk3 = 0xFFFFFFFFu,
           prk4 = 0xFFFFFFFFu, prk5 = 0xFFFFFFFFu, prk6 = 0xFFFFFFFFu, prk7 = 0xFFFFFFFFu;
  int jp = 0, jtprev = -1, jlprev = 0;

  for (int t = 0; t < N - 1; ++t) {
    int p = t & 1;
    int jt = j >> 3, jl = j & 7;

    // 1. issue this step's row load; pin issue order
    uint4 u = *(const uint4*)(D + (size_t)j * N + base);
    __builtin_amdgcn_sched_barrier(0);

    // 2. deferred md/par update with PREVIOUS row (reference step t-1 tail)
    #define DUPD(q) { bool up_ = prk##q < mdk##q; mdk##q = up_ ? prk##q : mdk##q; par##q = up_ ? jp : par##q; }
    DUPD(0) DUPD(1) DUPD(2) DUPD(3) DUPD(4) DUPD(5) DUPD(6) DUPD(7)
    #undef DUPD
    if (jtprev == tid) {   // re-INF at j_{t-1} (after min, like .at[j].set(inf))
      if      (jlprev == 0) mdk0 = INFK(base + 0);
      else if (jlprev == 1) mdk1 = INFK(base + 1);
      else if (jlprev == 2) mdk2 = INFK(base + 2);
      else if (jlprev == 3) mdk3 = INFK(base + 3);
      else if (jlprev == 4) mdk4 = INFK(base + 4);
      else if (jlprev == 5) mdk5 = INFK(base + 5);
      else if (jlprev == 6) mdk6 = INFK(base + 6);
      else                  mdk7 = INFK(base + 7);
    }

    // 3. record edge t (par == reference parent state at start of step t)
    if (jt == tid) {
      int pj = (jl == 0) ? par0 : (jl == 1) ? par1 : (jl == 2) ? par2 :
               (jl == 3) ? par3 : (jl == 4) ? par4 : (jl == 5) ? par5 :
               (jl == 6) ? par6 : par7;
      edges[t] = make_int2(pj, j);
    }

    // 4. eager INF at current j (update-comparison at j replayed next iter + re-INF)
    if (jt == tid) {
      if      (jl == 0) mdk0 = INFK(base + 0);
      else if (jl == 1) mdk1 = INFK(base + 1);
      else if (jl == 2) mdk2 = INFK(base + 2);
      else if (jl == 3) mdk3 = INFK(base + 3);
      else if (jl == 4) mdk4 = INFK(base + 4);
      else if (jl == 5) mdk5 = INFK(base + 5);
      else if (jl == 6) mdk6 = INFK(base + 6);
      else              mdk7 = INFK(base + 7);
    }

    // 5. A-tree over md keys (pure VALU, hidden under load)
    unsigned ak = umin2(umin2(umin2(mdk0, mdk1), umin2(mdk2, mdk3)),
                        umin2(umin2(mdk4, mdk5), umin2(mdk6, mdk7)));

    // 6. B: build fresh row keys (first use of u -> waitcnt lands here)
    prk0 = (u.x << 16) | (unsigned)(base + 0);
    prk1 = (u.x & 0xffff0000u) | (unsigned)(base + 1);
    prk2 = (u.y << 16) | (unsigned)(base + 2);
    prk3 = (u.y & 0xffff0000u) | (unsigned)(base + 3);
    prk4 = (u.z << 16) | (unsigned)(base + 4);
    prk5 = (u.z & 0xffff0000u) | (unsigned)(base + 5);
    prk6 = (u.w << 16) | (unsigned)(base + 6);
    prk7 = (u.w & 0xffff0000u) | (unsigned)(base + 7);
    {
      bool self = (jt == tid);
      unsigned b0 = (self && jl == 0) ? 0xFFFFFFFFu : prk0;
      unsigned b1 = (self && jl == 1) ? 0xFFFFFFFFu : prk1;
      unsigned b2 = (self && jl == 2) ? 0xFFFFFFFFu : prk2;
      unsigned b3 = (self && jl == 3) ? 0xFFFFFFFFu : prk3;
      unsigned b4 = (self && jl == 4) ? 0xFFFFFFFFu : prk4;
      unsigned b5 = (self && jl == 5) ? 0xFFFFFFFFu : prk5;
      unsigned b6 = (self && jl == 6) ? 0xFFFFFFFFu : prk6;
      unsigned b7 = (self && jl == 7) ? 0xFFFFFFFFu : prk7;
      unsigned bk = umin2(umin2(umin2(b0, b1), umin2(b2, b3)),
                          umin2(umin2(b4, b5), umin2(b6, b7)));
      unsigned x = umin2(ak, bk);
      x = dpp_umin<0xB1>(x);
      x = dpp_umin<0x4E>(x);
      x = dpp_umin<0x141>(x);
      x = dpp_umin<0x140>(x);
      unsigned r0 = (unsigned)__builtin_amdgcn_readlane((int)x, 0);
      unsigned r1 = (unsigned)__builtin_amdgcn_readlane((int)x, 16);
      unsigned r2 = (unsigned)__builtin_amdgcn_readlane((int)x, 32);
      unsigned r3 = (unsigned)__builtin_amdgcn_readlane((int)x, 48);
      unsigned wm = umin2(umin2(r0, r1), umin2(r2, r3));
      if (lane == 0) skey[p][w] = wm;
    }

    // 7. bookkeeping for the deferred update
    jp = j; jtprev = jt; jlprev = jl;

    // 8. single barrier; 8-slot u32 combine
    __syncthreads();
    uint4 A = ((const uint4*)&skey[p][0])[0];
    uint4 B = ((const uint4*)&skey[p][0])[1];
    unsigned k = umin2(umin2(umin2(A.x, A.y), umin2(A.z, A.w)),
                       umin2(umin2(B.x, B.y), umin2(B.z, B.w)));
    j = (int)(k & 0xFFFu);
  }
}

// ---------- final loss ----------
__global__ __launch_bounds__(1024) void loss_kernel(const __half* __restrict__ Dx,
                                                    const __half* __restrict__ Dz,
                                                    const int2* __restrict__ ex,
                                                    const int2* __restrict__ ez,
                                                    float* __restrict__ out) {
  int tid = threadIdx.x;
  float s = 0.f;
  const int M = N - 1;
  for (int e = tid; e < 2 * M; e += 1024) {
    int2 uv = (e < M) ? ex[e] : ez[e - M];
    size_t off = (size_t)uv.x * N + uv.y;
    float dx = __half2float(Dx[off]);
    float dz = __half2float(Dz[off]);
    float d = dx - dz;
    s += d * d;
  }
  for (int off = 32; off > 0; off >>= 1) s += __shfl_down(s, off);
  __shared__ float wsum[16];
  int lane = tid & 63, w = tid >> 6;
  if (lane == 0) wsum[w] = s;
  __syncthreads();
  if (tid == 0) {
    float t = 0.f;
    #pragma unroll
    for (int i = 0; i < 16; ++i) t += wsum[i];
    out[0] = 0.5f * t;
  }
}

// ---------- launch ----------
extern "C" void kernel_launch(void* const* d_in, const int* in_sizes, int n_in,
                              void* d_out, int out_size, void* d_ws, size_t ws_size,
                              hipStream_t stream) {
  const float* x = (const float*)d_in[0];
  const float* z = (const float*)d_in[1];
  float* out = (float*)d_out;
  char* ws = (char*)d_ws;

  __half* Dx = (__half*)ws;                       // 32 MB
  __half* Dz = Dx + (size_t)N * N;                // 32 MB
  short* Xb = (short*)(Dz + (size_t)N * N);       // 24 MB
  short* Zb = Xb + (size_t)N * KX;                // 1 MB
  float* sqx = (float*)(Zb + (size_t)N * KZ);
  float* sqz = sqx + N;
  int2* ex = (int2*)(sqz + N);
  int2* ez = ex + (N - 1);

  cvt_bf16_kernel<<<2048, 256, 0, stream>>>(x, Xb, N * KX / 8);
  cvt_bf16_kernel<<<256, 256, 0, stream>>>(z, Zb, N * KZ / 8);
  sqnorm_kernel<<<N, 256, 0, stream>>>(x, KX, sqx);
  sqnorm_kernel<<<N, 256, 0, stream>>>(z, KZ, sqz);
  dist_mfma_kernel<<<NTRI2, 256, 0, stream>>>(Xb, KX, sqx, Dx);
  dist_mfma_kernel<<<NTRI2, 256, 0, stream>>>(Zb, KZ, sqz, Dz);
  mst_kernel<<<2, 512, 0, stream>>>(Dx, Dz, ex, ez);
  loss_kernel<<<1, 1024, 0, stream>>>(Dx, Dz, ex, ez, out);
}

// Round 10
// 2594.584 us; speedup vs baseline: 2.1219x; 1.0249x over previous
//
#include <hip/hip_runtime.h>
#include <hip/hip_fp16.h>

#define N 4096
#define KX 3072
#define KZ 128
#define NBT (N / 128)               // 32 tile-rows for the MFMA dist kernel
#define NTRI2 (NBT * (NBT + 1) / 2) // 528 triangular tiles

typedef __attribute__((ext_vector_type(8))) short bf16x8;
typedef __attribute__((ext_vector_type(4))) float f32x4;

// ---------- helpers ----------
__device__ __forceinline__ short f2bf(float f) {  // RTN-even fp32 -> bf16
  unsigned u = __float_as_uint(f);
  u += 0x7fffu + ((u >> 16) & 1u);
  return (short)(u >> 16);
}

__device__ __forceinline__ unsigned umin2(unsigned a, unsigned b) { return a < b ? a : b; }

// DPP-based partial u32-min (within 16-lane rows); CTRL compile-time.
template <int CTRL>
__device__ __forceinline__ unsigned dpp_umin(unsigned x) {
  unsigned y = (unsigned)__builtin_amdgcn_update_dpp(0, (int)x, CTRL, 0xF, 0xF, true);
  return umin2(x, y);
}

// ---------- fp32 -> bf16 conversion (8 elems/thread, grid-stride) ----------
__global__ __launch_bounds__(256) void cvt_bf16_kernel(const float* __restrict__ X,
                                                       short* __restrict__ Xb, int n8) {
  int stride = gridDim.x * 256;
  for (int i = blockIdx.x * 256 + threadIdx.x; i < n8; i += stride) {
    float4 a = *(const float4*)(X + (size_t)i * 8);
    float4 b = *(const float4*)(X + (size_t)i * 8 + 4);
    bf16x8 o;
    o[0] = f2bf(a.x); o[1] = f2bf(a.y); o[2] = f2bf(a.z); o[3] = f2bf(a.w);
    o[4] = f2bf(b.x); o[5] = f2bf(b.y); o[6] = f2bf(b.z); o[7] = f2bf(b.w);
    *(bf16x8*)(Xb + (size_t)i * 8) = o;
  }
}

// ---------- row squared norms (exact fp32) ----------
__global__ __launch_bounds__(256) void sqnorm_kernel(const float* __restrict__ X, int K,
                                                     float* __restrict__ sq) {
  int row = blockIdx.x;
  const float4* xr = (const float4*)(X + (size_t)row * K);
  float s = 0.f;
  int n4 = K >> 2;
  for (int i = threadIdx.x; i < n4; i += 256) {
    float4 v = xr[i];
    s += v.x * v.x + v.y * v.y + v.z * v.z + v.w * v.w;
  }
  for (int off = 32; off > 0; off >>= 1) s += __shfl_down(s, off);
  __shared__ float wsum[4];
  int lane = threadIdx.x & 63, w = threadIdx.x >> 6;
  if (lane == 0) wsum[w] = s;
  __syncthreads();
  if (threadIdx.x == 0) {
    float t = 0.f;
    #pragma unroll
    for (int i = 0; i < 4; ++i) t += wsum[i];
    sq[row] = t;
  }
}

// ---------- MFMA bf16 distance GEMM (round-7 proven) ----------
__global__ __launch_bounds__(256) void dist_mfma_kernel(const short* __restrict__ Xb, int K,
                                                        const float* __restrict__ sq,
                                                        __half* __restrict__ D) {
  int t = blockIdx.x;
  int br = (int)((sqrtf(8.0f * (float)t + 1.0f) - 1.0f) * 0.5f);
  while ((br + 1) * (br + 2) / 2 <= t) ++br;
  while (br * (br + 1) / 2 > t) --br;
  int bc = t - br * (br + 1) / 2;
  int i0 = br * 128, j0 = bc * 128;

  __shared__ short As[128][40];
  __shared__ short Bs[128][40];

  int tid = threadIdx.x, lane = tid & 63, w = tid >> 6;
  int wr = w >> 1, wc = w & 1;
  int fr = lane & 15, fc = lane >> 4;

  f32x4 acc[4][4];
  #pragma unroll
  for (int m = 0; m < 4; ++m)
    #pragma unroll
    for (int nn = 0; nn < 4; ++nn)
      acc[m][nn] = (f32x4){0.f, 0.f, 0.f, 0.f};

  for (int k0 = 0; k0 < K; k0 += 32) {
    #pragma unroll
    for (int u = 0; u < 2; ++u) {
      int f = tid + u * 256;
      int r = f >> 2;
      int c = (f & 3) * 8;
      *(bf16x8*)&As[r][c] = *(const bf16x8*)(Xb + (size_t)(i0 + r) * K + k0 + c);
      *(bf16x8*)&Bs[r][c] = *(const bf16x8*)(Xb + (size_t)(j0 + r) * K + k0 + c);
    }
    __syncthreads();
    bf16x8 af[4], bg[4];
    #pragma unroll
    for (int m = 0; m < 4; ++m)
      af[m] = *(const bf16x8*)&As[wr * 64 + m * 16 + fr][fc * 8];
    #pragma unroll
    for (int nn = 0; nn < 4; ++nn)
      bg[nn] = *(const bf16x8*)&Bs[wc * 64 + nn * 16 + fr][fc * 8];
    #pragma unroll
    for (int m = 0; m < 4; ++m)
      #pragma unroll
      for (int nn = 0; nn < 4; ++nn)
        acc[m][nn] = __builtin_amdgcn_mfma_f32_16x16x32_bf16(af[m], bg[nn], acc[m][nn], 0, 0, 0);
    __syncthreads();
  }

  #pragma unroll
  for (int m = 0; m < 4; ++m) {
    #pragma unroll
    for (int nn = 0; nn < 4; ++nn) {
      int gj = j0 + wc * 64 + nn * 16 + fr;
      float sqj = sq[gj];
      #pragma unroll
      for (int e = 0; e < 4; ++e) {
        int gi = i0 + wr * 64 + m * 16 + fc * 4 + e;
        float d2 = sq[gi] + sqj - 2.0f * acc[m][nn][e];
        float d = sqrtf(fmaxf(d2, 0.0f));
        __half h = __float2half(d);
        D[(size_t)gi * N + gj] = h;
        D[(size_t)gj * N + gi] = h;
      }
    }
  }
}

// ---------- MST: u32-key deferred pipeline (exact reference semantics) ----------
// Round-9 structure + edge recording moved to LDS: the per-step edge
// global_store left a store outstanding in one wave; __syncthreads' implicit
// s_waitcnt vmcnt(0) then stalled that wave (and via the barrier, all waves)
// on store-ack each step. Edges now go to an LDS buffer (ds_write, covered by
// the barrier's lgkmcnt drain, ~free) and are dumped to global once at the end.
#define INFK(idx) (0xFFFF0000u | (unsigned)(idx))

__global__ __launch_bounds__(512) void mst_kernel(const __half* __restrict__ Dx,
                                                  const __half* __restrict__ Dz,
                                                  int2* __restrict__ ex,
                                                  int2* __restrict__ ez) {
  const __half* __restrict__ D = (blockIdx.x == 0) ? Dx : Dz;
  int2* __restrict__ edges = (blockIdx.x == 0) ? ex : ez;

  int tid = threadIdx.x;      // 0..511
  int lane = tid & 63;
  int w = tid >> 6;           // wave 0..7
  int base = tid * 8;         // nodes [base, base+8)

  unsigned mdk0, mdk1, mdk2, mdk3, mdk4, mdk5, mdk6, mdk7;
  int par0 = 0, par1 = 0, par2 = 0, par3 = 0, par4 = 0, par5 = 0, par6 = 0, par7 = 0;
  {
    uint4 u = *(const uint4*)(D + base);
    mdk0 = (u.x << 16) | (unsigned)(base + 0);
    mdk1 = (u.x & 0xffff0000u) | (unsigned)(base + 1);
    mdk2 = (u.y << 16) | (unsigned)(base + 2);
    mdk3 = (u.y & 0xffff0000u) | (unsigned)(base + 3);
    mdk4 = (u.z << 16) | (unsigned)(base + 4);
    mdk5 = (u.z & 0xffff0000u) | (unsigned)(base + 5);
    mdk6 = (u.w << 16) | (unsigned)(base + 6);
    mdk7 = (u.w & 0xffff0000u) | (unsigned)(base + 7);
  }
  if (tid == 0) mdk0 = INFK(0);  // node 0 starts in tree

  __shared__ unsigned skey[2][8];
  __shared__ uint2 eld[N - 1];   // edge buffer (32 KB LDS)

  // ---- prologue: j0 = argmin(initial md)
  int j;
  {
    unsigned x = umin2(umin2(umin2(mdk0, mdk1), umin2(mdk2, mdk3)),
                       umin2(umin2(mdk4, mdk5), umin2(mdk6, mdk7)));
    x = dpp_umin<0xB1>(x);   // xor 1
    x = dpp_umin<0x4E>(x);   // xor 2
    x = dpp_umin<0x141>(x);  // xor 4 (row_half_mirror)
    x = dpp_umin<0x140>(x);  // xor 8 (row_mirror)
    unsigned r0 = (unsigned)__builtin_amdgcn_readlane((int)x, 0);
    unsigned r1 = (unsigned)__builtin_amdgcn_readlane((int)x, 16);
    unsigned r2 = (unsigned)__builtin_amdgcn_readlane((int)x, 32);
    unsigned r3 = (unsigned)__builtin_amdgcn_readlane((int)x, 48);
    unsigned wm = umin2(umin2(r0, r1), umin2(r2, r3));
    if (lane == 0) skey[1][w] = wm;
    __syncthreads();
    uint4 A = ((const uint4*)&skey[1][0])[0];
    uint4 B = ((const uint4*)&skey[1][0])[1];
    unsigned k = umin2(umin2(umin2(A.x, A.y), umin2(A.z, A.w)),
                       umin2(umin2(B.x, B.y), umin2(B.z, B.w)));
    j = (int)(k & 0xFFFu);
  }

  // carried state: previous row keys (true values) + its position
  unsigned prk0 = 0xFFFFFFFFu, prk1 = 0xFFFFFFFFu, prk2 = 0xFFFFFFFFu, prk3 = 0xFFFFFFFFu,
           prk4 = 0xFFFFFFFFu, prk5 = 0xFFFFFFFFu, prk6 = 0xFFFFFFFFu, prk7 = 0xFFFFFFFFu;
  int jp = 0, jtprev = -1, jlprev = 0;

  for (int t = 0; t < N - 1; ++t) {
    int p = t & 1;
    int jt = j >> 3, jl = j & 7;

    // 1. issue this step's row load; pin issue order
    uint4 u = *(const uint4*)(D + (size_t)j * N + base);
    __builtin_amdgcn_sched_barrier(0);

    // 2. deferred md/par update with PREVIOUS row (reference step t-1 tail)
    #define DUPD(q) { bool up_ = prk##q < mdk##q; mdk##q = up_ ? prk##q : mdk##q; par##q = up_ ? jp : par##q; }
    DUPD(0) DUPD(1) DUPD(2) DUPD(3) DUPD(4) DUPD(5) DUPD(6) DUPD(7)
    #undef DUPD
    if (jtprev == tid) {   // re-INF at j_{t-1} (after min, like .at[j].set(inf))
      if      (jlprev == 0) mdk0 = INFK(base + 0);
      else if (jlprev == 1) mdk1 = INFK(base + 1);
      else if (jlprev == 2) mdk2 = INFK(base + 2);
      else if (jlprev == 3) mdk3 = INFK(base + 3);
      else if (jlprev == 4) mdk4 = INFK(base + 4);
      else if (jlprev == 5) mdk5 = INFK(base + 5);
      else if (jlprev == 6) mdk6 = INFK(base + 6);
      else                  mdk7 = INFK(base + 7);
    }

    // 3. record edge t into LDS (no global store in the loop!)
    if (jt == tid) {
      int pj = (jl == 0) ? par0 : (jl == 1) ? par1 : (jl == 2) ? par2 :
               (jl == 3) ? par3 : (jl == 4) ? par4 : (jl == 5) ? par5 :
               (jl == 6) ? par6 : par7;
      eld[t] = make_uint2((unsigned)pj, (unsigned)j);
    }

    // 4. eager INF at current j
    if (jt == tid) {
      if      (jl == 0) mdk0 = INFK(base + 0);
      else if (jl == 1) mdk1 = INFK(base + 1);
      else if (jl == 2) mdk2 = INFK(base + 2);
      else if (jl == 3) mdk3 = INFK(base + 3);
      else if (jl == 4) mdk4 = INFK(base + 4);
      else if (jl == 5) mdk5 = INFK(base + 5);
      else if (jl == 6) mdk6 = INFK(base + 6);
      else              mdk7 = INFK(base + 7);
    }

    // 5. A-tree over md keys (pure VALU, hidden under load)
    unsigned ak = umin2(umin2(umin2(mdk0, mdk1), umin2(mdk2, mdk3)),
                        umin2(umin2(mdk4, mdk5), umin2(mdk6, mdk7)));

    // 6. B: build fresh row keys (first use of u -> waitcnt lands here)
    prk0 = (u.x << 16) | (unsigned)(base + 0);
    prk1 = (u.x & 0xffff0000u) | (unsigned)(base + 1);
    prk2 = (u.y << 16) | (unsigned)(base + 2);
    prk3 = (u.y & 0xffff0000u) | (unsigned)(base + 3);
    prk4 = (u.z << 16) | (unsigned)(base + 4);
    prk5 = (u.z & 0xffff0000u) | (unsigned)(base + 5);
    prk6 = (u.w << 16) | (unsigned)(base + 6);
    prk7 = (u.w & 0xffff0000u) | (unsigned)(base + 7);
    {
      bool self = (jt == tid);
      unsigned b0 = (self && jl == 0) ? 0xFFFFFFFFu : prk0;
      unsigned b1 = (self && jl == 1) ? 0xFFFFFFFFu : prk1;
      unsigned b2 = (self && jl == 2) ? 0xFFFFFFFFu : prk2;
      unsigned b3 = (self && jl == 3) ? 0xFFFFFFFFu : prk3;
      unsigned b4 = (self && jl == 4) ? 0xFFFFFFFFu : prk4;
      unsigned b5 = (self && jl == 5) ? 0xFFFFFFFFu : prk5;
      unsigned b6 = (self && jl == 6) ? 0xFFFFFFFFu : prk6;
      unsigned b7 = (self && jl == 7) ? 0xFFFFFFFFu : prk7;
      unsigned bk = umin2(umin2(umin2(b0, b1), umin2(b2, b3)),
                          umin2(umin2(b4, b5), umin2(b6, b7)));
      unsigned x = umin2(ak, bk);
      x = dpp_umin<0xB1>(x);
      x = dpp_umin<0x4E>(x);
      x = dpp_umin<0x141>(x);
      x = dpp_umin<0x140>(x);
      unsigned r0 = (unsigned)__builtin_amdgcn_readlane((int)x, 0);
      unsigned r1 = (unsigned)__builtin_amdgcn_readlane((int)x, 16);
      unsigned r2 = (unsigned)__builtin_amdgcn_readlane((int)x, 32);
      unsigned r3 = (unsigned)__builtin_amdgcn_readlane((int)x, 48);
      unsigned wm = umin2(umin2(r0, r1), umin2(r2, r3));
      if (lane == 0) skey[p][w] = wm;
    }

    // 7. bookkeeping for the deferred update
    jp = j; jtprev = jt; jlprev = jl;

    // 8. single barrier; 8-slot u32 combine
    __syncthreads();
    uint4 A = ((const uint4*)&skey[p][0])[0];
    uint4 B = ((const uint4*)&skey[p][0])[1];
    unsigned k = umin2(umin2(umin2(A.x, A.y), umin2(A.z, A.w)),
                       umin2(umin2(B.x, B.y), umin2(B.z, B.w)));
    j = (int)(k & 0xFFFu);
  }

  // ---- dump edges LDS -> global (coalesced)
  __syncthreads();
  for (int e = tid; e < N - 1; e += 512) {
    uint2 v = eld[e];
    edges[e] = make_int2((int)v.x, (int)v.y);
  }
}

// ---------- final loss ----------
__global__ __launch_bounds__(1024) void loss_kernel(const __half* __restrict__ Dx,
                                                    const __half* __restrict__ Dz,
                                                    const int2* __restrict__ ex,
                                                    const int2* __restrict__ ez,
                                                    float* __restrict__ out) {
  int tid = threadIdx.x;
  float s = 0.f;
  const int M = N - 1;
  for (int e = tid; e < 2 * M; e += 1024) {
    int2 uv = (e < M) ? ex[e] : ez[e - M];
    size_t off = (size_t)uv.x * N + uv.y;
    float dx = __half2float(Dx[off]);
    float dz = __half2float(Dz[off]);
    float d = dx - dz;
    s += d * d;
  }
  for (int off = 32; off > 0; off >>= 1) s += __shfl_down(s, off);
  __shared__ float wsum[16];
  int lane = tid & 63, w = tid >> 6;
  if (lane == 0) wsum[w] = s;
  __syncthreads();
  if (tid == 0) {
    float t = 0.f;
    #pragma unroll
    for (int i = 0; i < 16; ++i) t += wsum[i];
    out[0] = 0.5f * t;
  }
}

// ---------- launch ----------
extern "C" void kernel_launch(void* const* d_in, const int* in_sizes, int n_in,
                              void* d_out, int out_size, void* d_ws, size_t ws_size,
                              hipStream_t stream) {
  const float* x = (const float*)d_in[0];
  const float* z = (const float*)d_in[1];
  float* out = (float*)d_out;
  char* ws = (char*)d_ws;

  __half* Dx = (__half*)ws;                       // 32 MB
  __half* Dz = Dx + (size_t)N * N;                // 32 MB
  short* Xb = (short*)(Dz + (size_t)N * N);       // 24 MB
  short* Zb = Xb + (size_t)N * KX;                // 1 MB
  float* sqx = (float*)(Zb + (size_t)N * KZ);
  float* sqz = sqx + N;
  int2* ex = (int2*)(sqz + N);
  int2* ez = ex + (N - 1);

  cvt_bf16_kernel<<<2048, 256, 0, stream>>>(x, Xb, N * KX / 8);
  cvt_bf16_kernel<<<256, 256, 0, stream>>>(z, Zb, N * KZ / 8);
  sqnorm_kernel<<<N, 256, 0, stream>>>(x, KX, sqx);
  sqnorm_kernel<<<N, 256, 0, stream>>>(z, KZ, sqz);
  dist_mfma_kernel<<<NTRI2, 256, 0, stream>>>(Xb, KX, sqx, Dx);
  dist_mfma_kernel<<<NTRI2, 256, 0, stream>>>(Zb, KZ, sqz, Dz);
  mst_kernel<<<2, 512, 0, stream>>>(Dx, Dz, ex, ez);
  loss_kernel<<<1, 1024, 0, stream>>>(Dx, Dz, ex, ez, out);
}